// Round 1
// baseline (778.148 us; speedup 1.0000x reference)
//
#include <hip/hip_runtime.h>

// MoE combine: out[token_idx[r]] += gates[r] * expert_hidden[r]
// NUM_ROWS=32768, HIDDEN=4096, NUM_TOKENS=16384, all fp32.

#define HIDDEN      4096
#define H4          (HIDDEN / 4)   // 1024 float4 per row
#define NUM_TOKENS  16384
#define CAP         32             // slots per token (mean 2, Poisson tail safe)

__global__ __launch_bounds__(256) void moe_zero_counts(int* __restrict__ counts) {
    int i = blockIdx.x * blockDim.x + threadIdx.x;
    if (i < NUM_TOKENS) counts[i] = 0;
}

__global__ __launch_bounds__(256) void moe_build_lists(
        const int* __restrict__ token_idx,
        int* __restrict__ counts,
        int* __restrict__ row_list,
        int num_rows) {
    int r = blockIdx.x * blockDim.x + threadIdx.x;
    if (r < num_rows) {
        int t = token_idx[r];
        int pos = atomicAdd(&counts[t], 1);
        if (pos < CAP) row_list[t * CAP + pos] = r;
    }
}

__global__ __launch_bounds__(256) void moe_combine(
        const float4* __restrict__ eh4,
        const float*  __restrict__ gates,
        const int*    __restrict__ counts,
        const int*    __restrict__ row_list,
        float4*       __restrict__ out4) {
    const int t   = blockIdx.x;
    const int tid = threadIdx.x;

    int n = counts[t];
    if (n > CAP) n = CAP;

    float4 a0 = {0.f, 0.f, 0.f, 0.f};
    float4 a1 = {0.f, 0.f, 0.f, 0.f};
    float4 a2 = {0.f, 0.f, 0.f, 0.f};
    float4 a3 = {0.f, 0.f, 0.f, 0.f};

    for (int i = 0; i < n; ++i) {
        // Block-uniform values -> scalar loads on gfx950.
        int   r = row_list[t * CAP + i];
        float g = gates[r];
        const float4* row = eh4 + (size_t)r * H4;

        float4 v0 = row[tid];
        float4 v1 = row[tid + 256];
        float4 v2 = row[tid + 512];
        float4 v3 = row[tid + 768];

        a0.x += g * v0.x; a0.y += g * v0.y; a0.z += g * v0.z; a0.w += g * v0.w;
        a1.x += g * v1.x; a1.y += g * v1.y; a1.z += g * v1.z; a1.w += g * v1.w;
        a2.x += g * v2.x; a2.y += g * v2.y; a2.z += g * v2.z; a2.w += g * v2.w;
        a3.x += g * v3.x; a3.y += g * v3.y; a3.z += g * v3.z; a3.w += g * v3.w;
    }

    float4* orow = out4 + (size_t)t * H4;
    orow[tid]       = a0;
    orow[tid + 256] = a1;
    orow[tid + 512] = a2;
    orow[tid + 768] = a3;
}

extern "C" void kernel_launch(void* const* d_in, const int* in_sizes, int n_in,
                              void* d_out, int out_size, void* d_ws, size_t ws_size,
                              hipStream_t stream) {
    const float* expert_hidden = (const float*)d_in[0];
    const int*   token_idx     = (const int*)d_in[1];
    const float* gates         = (const float*)d_in[2];
    float*       out           = (float*)d_out;

    const int num_rows = in_sizes[1];  // 32768

    // Workspace layout: [counts: NUM_TOKENS ints][row_list: NUM_TOKENS*CAP ints]
    int* counts   = (int*)d_ws;
    int* row_list = counts + NUM_TOKENS;

    moe_zero_counts<<<(NUM_TOKENS + 255) / 256, 256, 0, stream>>>(counts);

    moe_build_lists<<<(num_rows + 255) / 256, 256, 0, stream>>>(
        token_idx, counts, row_list, num_rows);

    moe_combine<<<NUM_TOKENS, 256, 0, stream>>>(
        (const float4*)expert_hidden, gates, counts, row_list, (float4*)out);
}

// Round 2
// 751.637 us; speedup vs baseline: 1.0353x; 1.0353x over previous
//
#include <hip/hip_runtime.h>

// MoE combine: out[token_idx[r]] += gates[r] * expert_hidden[r]
// NUM_ROWS=32768, HIDDEN=4096, NUM_TOKENS=16384, all fp32.
//
// Strategy: invert scatter->gather. Bucket rows per token (atomic histogram,
// tiny), then one block per token streams its rows (avg 2, Poisson) and does
// one clean nontemporal store. No RMW on the 256 MiB output, no zero-init
// pass over it, and the 512 MiB input is read exactly once -> nt loads.

#define HIDDEN      4096
#define H4          (HIDDEN / 4)   // 1024 float4 per row
#define NUM_TOKENS  16384
#define CAP         32             // slots per token (mean 2, Poisson tail safe)

typedef float f4 __attribute__((ext_vector_type(4)));

__device__ __forceinline__ f4 ntload(const f4* p) {
    return __builtin_nontemporal_load(p);
}

__global__ __launch_bounds__(256) void moe_zero_counts(int* __restrict__ counts) {
    int i = blockIdx.x * blockDim.x + threadIdx.x;
    if (i < NUM_TOKENS) counts[i] = 0;
}

__global__ __launch_bounds__(256) void moe_build_lists(
        const int* __restrict__ token_idx,
        int* __restrict__ counts,
        int* __restrict__ row_list,
        int num_rows) {
    int r = blockIdx.x * blockDim.x + threadIdx.x;
    if (r < num_rows) {
        int t = token_idx[r];
        int pos = atomicAdd(&counts[t], 1);
        if (pos < CAP) row_list[t * CAP + pos] = r;
    }
}

__global__ __launch_bounds__(256) void moe_combine(
        const f4*    __restrict__ eh,
        const float* __restrict__ gates,
        const int*   __restrict__ counts,
        const int*   __restrict__ row_list,
        f4*          __restrict__ out) {
    const int t   = blockIdx.x;
    const int tid = threadIdx.x;

    int n = counts[t];
    if (n > CAP) n = CAP;

    f4 a0 = {0.f, 0.f, 0.f, 0.f};
    f4 a1 = {0.f, 0.f, 0.f, 0.f};
    f4 a2 = {0.f, 0.f, 0.f, 0.f};
    f4 a3 = {0.f, 0.f, 0.f, 0.f};

    const int* my_list = row_list + t * CAP;

    int i = 0;
    // Unrolled by 2 rows: 8 outstanding 16B loads per wave -> better MLP.
    for (; i + 2 <= n; i += 2) {
        int   r0 = my_list[i];
        int   r1 = my_list[i + 1];
        float g0 = gates[r0];
        float g1 = gates[r1];
        const f4* p0 = eh + (size_t)r0 * H4;
        const f4* p1 = eh + (size_t)r1 * H4;

        f4 u0 = ntload(p0 + tid);
        f4 u1 = ntload(p0 + tid + 256);
        f4 u2 = ntload(p0 + tid + 512);
        f4 u3 = ntload(p0 + tid + 768);
        f4 w0 = ntload(p1 + tid);
        f4 w1 = ntload(p1 + tid + 256);
        f4 w2 = ntload(p1 + tid + 512);
        f4 w3 = ntload(p1 + tid + 768);

        a0 += g0 * u0; a1 += g0 * u1; a2 += g0 * u2; a3 += g0 * u3;
        a0 += g1 * w0; a1 += g1 * w1; a2 += g1 * w2; a3 += g1 * w3;
    }
    if (i < n) {
        int   r0 = my_list[i];
        float g0 = gates[r0];
        const f4* p0 = eh + (size_t)r0 * H4;

        f4 u0 = ntload(p0 + tid);
        f4 u1 = ntload(p0 + tid + 256);
        f4 u2 = ntload(p0 + tid + 512);
        f4 u3 = ntload(p0 + tid + 768);

        a0 += g0 * u0; a1 += g0 * u1; a2 += g0 * u2; a3 += g0 * u3;
    }

    f4* orow = out + (size_t)t * H4;
    __builtin_nontemporal_store(a0, orow + tid);
    __builtin_nontemporal_store(a1, orow + tid + 256);
    __builtin_nontemporal_store(a2, orow + tid + 512);
    __builtin_nontemporal_store(a3, orow + tid + 768);
}

extern "C" void kernel_launch(void* const* d_in, const int* in_sizes, int n_in,
                              void* d_out, int out_size, void* d_ws, size_t ws_size,
                              hipStream_t stream) {
    const float* expert_hidden = (const float*)d_in[0];
    const int*   token_idx     = (const int*)d_in[1];
    const float* gates         = (const float*)d_in[2];

    const int num_rows = in_sizes[1];  // 32768

    // Workspace layout: [counts: NUM_TOKENS ints][row_list: NUM_TOKENS*CAP ints]
    int* counts   = (int*)d_ws;
    int* row_list = counts + NUM_TOKENS;

    moe_zero_counts<<<(NUM_TOKENS + 255) / 256, 256, 0, stream>>>(counts);

    moe_build_lists<<<(num_rows + 255) / 256, 256, 0, stream>>>(
        token_idx, counts, row_list, num_rows);

    moe_combine<<<NUM_TOKENS, 256, 0, stream>>>(
        (const f4*)expert_hidden, gates, counts, row_list, (f4*)d_out);
}